// Round 14
// baseline (102.751 us; speedup 1.0000x reference)
//
#include <hip/hip_runtime.h>
#include <hip/hip_fp16.h>

#define NB    8
#define NDET  128
#define NT    2048
#define NPIX  65536            // 256*256
#define NELEM (NDET * NT)      // 262144 per batch
#define NGRP  32               // detector groups of 4

typedef int          i32x4 __attribute__((ext_vector_type(4)));
typedef float        f32x4 __attribute__((ext_vector_type(4)));
typedef unsigned int u32x4 __attribute__((ext_vector_type(4)));

// ws layout (bytes):
//   0       : double partials [256][2]  (sum, sumsq per reduction block)
//   4096    : float  wsf[0..7] mean, [8..15] inv_std, uint [16] valid-mode,
//             [17] 1/norm, [32..159] apodn[d]
//   8192    : __half S16[NDET][NT][NB]  (4 MiB)
//   +4M     : __half pS[8][NPIX][NB]  (8 MiB)  -- per-XCD-slice partials
//             (das2 fallback reuses this region as float partials[8][NB][NPIX])

#define WS_S16_OFF   8192
#define WS_PT_OFF    (8192 + (size_t)NDET * NT * NB * 2)
#define WS11_REQUIRED (WS_PT_OFF + (size_t)8 * NPIX * NB * 2)

__global__ __launch_bounds__(256) void k_stats(const float* __restrict__ sino,
                                               double* __restrict__ wsd) {
    const int bx = blockIdx.x;            // 0..255
    const int b = bx >> 5, i = bx & 31;   // batch, chunk
    const float4* src = (const float4*)(sino + (size_t)b * NELEM);
    const int base = i * 2048;            // 2048 float4 per chunk
    double s = 0.0, ss = 0.0;
    for (int r = 0; r < 8; ++r) {
        float4 v = src[base + r * 256 + threadIdx.x];
        double d0 = v.x, d1 = v.y, d2 = v.z, d3 = v.w;
        s  += d0 + d1 + d2 + d3;
        ss += d0 * d0 + d1 * d1 + d2 * d2 + d3 * d3;
    }
    for (int off = 32; off; off >>= 1) {
        s  += __shfl_down(s, off);
        ss += __shfl_down(ss, off);
    }
    __shared__ double lds[8];
    const int wave = threadIdx.x >> 6;
    if ((threadIdx.x & 63) == 0) { lds[wave * 2] = s; lds[wave * 2 + 1] = ss; }
    __syncthreads();
    if (threadIdx.x == 0) {
        double S = 0, SS = 0;
        for (int w = 0; w < 4; ++w) { S += lds[w * 2]; SS += lds[w * 2 + 1]; }
        wsd[bx * 2] = S; wsd[bx * 2 + 1] = SS;
    }
}

__global__ __launch_bounds__(256) void k_finalize(const float* __restrict__ apod,
                                                  const unsigned char* __restrict__ validb,
                                                  const double* __restrict__ wsd,
                                                  float* __restrict__ wsf) {
    __shared__ float sap[NDET];
    __shared__ int sflag;
    const int t = threadIdx.x;
    if (t == 0) sflag = 0;
    if (t < NDET) sap[t] = apod[t];
    // Detect `valid` element width. numpy bool -> 1 byte/elem: bytes at
    // offset%4==1 are ~99% ones somewhere in 64KB. int32/f32: always 0.
    int local = 0;
    {
        const unsigned char* vb = validb + t * 256;
        for (int j = 1; j < 256; j += 4) local |= (vb[j] != 0);
    }
    __syncthreads();
    if (local) atomicOr(&sflag, 1);
    if (t < NB) {
        double S = 0, SS = 0;
        for (int i = 0; i < 32; ++i) {
            S  += wsd[(t * 32 + i) * 2];
            SS += wsd[(t * 32 + i) * 2 + 1];
        }
        double mean = S / (double)NELEM;
        double var  = SS / (double)NELEM - mean * mean;
        double istd = 1.0 / sqrt(var + (double)(1.1920928955078125e-07f));
        wsf[t]     = (float)mean;
        wsf[8 + t] = (float)istd;
    }
    if (t == 0) {
        double a = 0;
        for (int d = 0; d < NDET; ++d) a += (double)sap[d];
        float norm = fmaxf((float)a, 1.1754943508222875e-38f);
        wsf[17] = 1.0f / norm;
    }
    __syncthreads();
    if (t < NDET) wsf[32 + t] = sap[t] * wsf[17];
    if (t == 0) ((unsigned int*)wsf)[16] = (unsigned int)(sflag != 0);
}

__global__ __launch_bounds__(256) void k_build(const float* __restrict__ sino,
                                               const float* __restrict__ wsf,
                                               __half* __restrict__ S16) {
    const int dt = blockIdx.x * 256 + threadIdx.x;   // d*NT + t
    union { uint4 q; __half h[8]; } u;
#pragma unroll
    for (int b = 0; b < NB; ++b) {
        float x = sino[(size_t)b * NELEM + dt];
        u.h[b] = __float2half((x - wsf[b]) * wsf[8 + b]);
    }
    *(uint4*)(S16 + (size_t)dt * 8) = u.q;
}

__device__ __forceinline__ float2 h2f(unsigned int w) {
    __half2 h;
    *reinterpret_cast<unsigned int*>(&h) = w;
    return __half22float2(h);
}

// ---- das11: fused pack+gather, no pk round-trip, no big LDS, no barriers.
// XCD x = blockIdx&7 owns dets [16x,16x+16) -> its 512KB S16 slice stays hot
// in the XCD-local L2 (shared by all 256 blocks of that XCD). Thread
// (gsub=tid&3, pl=tid>>2) handles 4 units (unit = pixel x det-quad):
//   p = c*256 + i*64 + pl, g = x*4+gsub.
// LUT reads: 16B quad per lane; lanes of one pixel are 16B-consecutive ->
// 16 fully-used 64B lines per wave-instr (pack's proven-dense pattern).
// NONTEMPORAL loads keep the single-use LUT stream from evicting S16.
// Gathers: 8x uint4 from L2-hot slice. In-lane 4-det sum + shfl_xor over
// gsub -> one fp16x8 partial per (XCD-slice, pixel): pS[8][NPIX][8] = 8MB.
__global__ __launch_bounds__(256, 4) void k_das11(const int* __restrict__ k0,
                                                  const float* __restrict__ alpha,
                                                  const void* __restrict__ valid,
                                                  const __half* __restrict__ S16,
                                                  const float* __restrict__ wsf,
                                                  uint4* __restrict__ pS) {
    const int x = blockIdx.x & 7;
    const int c = blockIdx.x >> 3;            // 0..255
    const int gsub = threadIdx.x & 3;
    const int pl   = threadIdx.x >> 2;        // 0..63
    const int g    = x * 4 + gsub;
    const unsigned int mode = ((const unsigned int*)wsf)[16];
    float apn[4];
#pragma unroll
    for (int j = 0; j < 4; ++j) apn[j] = wsf[32 + g * 4 + j];

    const __half* Sg = S16;                   // full table; slice is L2-hot

    i32x4 kq; f32x4 aq; unsigned int vq;
    {
        const size_t e = ((size_t)(c * 256 + pl) * NDET) + g * 4;
        kq = __builtin_nontemporal_load((const i32x4*)(k0 + e));
        aq = __builtin_nontemporal_load((const f32x4*)(alpha + e));
        if (mode) {
            vq = __builtin_nontemporal_load((const unsigned int*)((const unsigned char*)valid + e));
        } else {
            u32x4 v = __builtin_nontemporal_load((const u32x4*)((const unsigned int*)valid + e));
            vq = (v.x ? 1u : 0u) | (v.y ? 2u : 0u) | (v.z ? 4u : 0u) | (v.w ? 8u : 0u);
        }
    }

    for (int i = 0; i < 4; ++i) {
        const i32x4        kc = kq;
        const f32x4        ac = aq;
        unsigned int       vc = vq;
        if (i < 3) {                          // prefetch next unit's LUT
            const size_t e = ((size_t)(c * 256 + (i + 1) * 64 + pl) * NDET) + g * 4;
            kq = __builtin_nontemporal_load((const i32x4*)(k0 + e));
            aq = __builtin_nontemporal_load((const f32x4*)(alpha + e));
            if (mode) {
                vq = __builtin_nontemporal_load((const unsigned int*)((const unsigned char*)valid + e));
            } else {
                u32x4 v = __builtin_nontemporal_load((const u32x4*)((const unsigned int*)valid + e));
                vq = (v.x ? 1u : 0u) | (v.y ? 2u : 0u) | (v.z ? 4u : 0u) | (v.w ? 8u : 0u);
            }
        }
        if (mode)
            vc = ((vc & 0xffu) ? 1u : 0u) | ((vc & 0xff00u) ? 2u : 0u) |
                 ((vc & 0xff0000u) ? 4u : 0u) | ((vc & 0xff000000u) ? 8u : 0u);

        const int   kk[4] = {kc.x, kc.y, kc.z, kc.w};
        const float aa[4] = {ac.x, ac.y, ac.z, ac.w};
        // issue all 8 gathers (L2-hot), then consume
        uint4 q0[4], q1[4];
#pragma unroll
        for (int j = 0; j < 4; ++j) {
            const int d = g * 4 + j;
            const uint4* s = (const uint4*)(Sg + ((size_t)(d * NT + kk[j]) << 3));
            q0[j] = s[0];
            q1[j] = s[1];
        }
        float acc[NB] = {0.f, 0.f, 0.f, 0.f, 0.f, 0.f, 0.f, 0.f};
#pragma unroll
        for (int j = 0; j < 4; ++j) {
            const float w  = ((vc >> j) & 1u) ? apn[j] : 0.0f;
            const float wb = w * aa[j];
            const float wa = w - wb;
            const unsigned int w0[4] = {q0[j].x, q0[j].y, q0[j].z, q0[j].w};
            const unsigned int w1[4] = {q1[j].x, q1[j].y, q1[j].z, q1[j].w};
#pragma unroll
            for (int h = 0; h < 4; ++h) {
                float2 f0 = h2f(w0[h]);
                float2 f1 = h2f(w1[h]);
                acc[2 * h]     += wa * f0.x + wb * f1.x;
                acc[2 * h + 1] += wa * f0.y + wb * f1.y;
            }
        }
        // reduce over the 4 group-lanes (gsub = lane bits 0-1)
#pragma unroll
        for (int b = 0; b < NB; ++b) {
            acc[b] += __shfl_xor(acc[b], 1);
            acc[b] += __shfl_xor(acc[b], 2);
        }
        if (gsub == 0) {
            union { uint4 q; __half2 h[4]; } o;
#pragma unroll
            for (int h = 0; h < 4; ++h)
                o.h[h] = __floats2half2_rn(acc[2 * h], acc[2 * h + 1]);
            const int p = c * 256 + i * 64 + pl;
            pS[(size_t)x * NPIX + p] = o.q;
        }
    }
}

__global__ __launch_bounds__(256) void k_reduce3(const uint4* __restrict__ pS,
                                                 float* __restrict__ out) {
    const int p = blockIdx.x * 256 + threadIdx.x;
    float acc[NB] = {0.f, 0.f, 0.f, 0.f, 0.f, 0.f, 0.f, 0.f};
#pragma unroll
    for (int x = 0; x < 8; ++x) {
        union { uint4 q; __half2 h[4]; } u;
        u.q = pS[(size_t)x * NPIX + p];
#pragma unroll
        for (int h = 0; h < 4; ++h) {
            float2 f = __half22float2(u.h[h]);
            acc[2 * h]     += f.x;
            acc[2 * h + 1] += f.y;
        }
    }
#pragma unroll
    for (int b = 0; b < NB; ++b)
        out[(size_t)b * NPIX + p] = acc[b];
}

// ---- fallback: XCD-sliced L2-gather DAS (round-2 kernel) ----
__global__ __launch_bounds__(1024) void k_das2(const int* __restrict__ k0,
                                               const float* __restrict__ alpha,
                                               const void* __restrict__ valid,
                                               const __half* __restrict__ S16,
                                               const float* __restrict__ wsf,
                                               float* __restrict__ partials) {
    const int px = threadIdx.x & 255;
    const int dc = threadIdx.x >> 8;
    const int slice = blockIdx.x & 7;
    const int chunk = blockIdx.x >> 3;
    const int p  = chunk * 256 + px;
    const int d0 = slice * 16 + dc * 4;
    const unsigned int mode = ((const unsigned int*)wsf)[16];
    const float* apodn = wsf + 32;

    float acc[NB] = {0.f, 0.f, 0.f, 0.f, 0.f, 0.f, 0.f, 0.f};
    const size_t lbase = (size_t)p * NDET + d0;

    int4   k4 = *(const int4*)(k0 + lbase);
    float4 a4 = *(const float4*)(alpha + lbase);
    unsigned int vbits;
    if (mode) {
        unsigned int v4 = *(const unsigned int*)((const unsigned char*)valid + lbase);
        vbits = ((v4 & 0xffu) ? 1u : 0u) | (((v4 >> 8) & 0xffu) ? 2u : 0u) |
                (((v4 >> 16) & 0xffu) ? 4u : 0u) | ((v4 >> 24) ? 8u : 0u);
    } else {
        uint4 v4 = *(const uint4*)((const unsigned int*)valid + lbase);
        vbits = (v4.x ? 1u : 0u) | (v4.y ? 2u : 0u) | (v4.z ? 4u : 0u) | (v4.w ? 8u : 0u);
    }
    const int   kk[4] = {k4.x, k4.y, k4.z, k4.w};
    const float aa[4] = {a4.x, a4.y, a4.z, a4.w};
#pragma unroll
    for (int j = 0; j < 4; ++j) {
        const int d = d0 + j;
        const float w  = ((vbits >> j) & 1u) ? apodn[d] : 0.0f;
        const float wb = w * aa[j];
        const float wa = w - wb;
        const uint4* s = (const uint4*)(S16 + ((size_t)(d * NT + kk[j]) << 3));
        uint4 q0 = s[0];
        uint4 q1 = s[1];
        const unsigned int w0[4] = {q0.x, q0.y, q0.z, q0.w};
        const unsigned int w1[4] = {q1.x, q1.y, q1.z, q1.w};
#pragma unroll
        for (int h = 0; h < 4; ++h) {
            float2 f0 = h2f(w0[h]);
            float2 f1 = h2f(w1[h]);
            acc[2 * h]     += wa * f0.x + wb * f1.x;
            acc[2 * h + 1] += wa * f0.y + wb * f1.y;
        }
    }

    __shared__ float red[1024][9];
#pragma unroll
    for (int b = 0; b < NB; ++b) red[threadIdx.x][b] = acc[b];
    __syncthreads();
    if (dc == 0) {
#pragma unroll
        for (int b = 0; b < NB; ++b) {
            float v = red[px][b] + red[px + 256][b] + red[px + 512][b] + red[px + 768][b];
            partials[((size_t)slice * NB + b) * NPIX + p] = v;
        }
    }
}

__global__ __launch_bounds__(256) void k_reduce(const float* __restrict__ partials,
                                                float* __restrict__ out) {
    const int i = (blockIdx.x * 256 + threadIdx.x) * 4;
    float4 s = {0.f, 0.f, 0.f, 0.f};
#pragma unroll
    for (int g = 0; g < 8; ++g) {
        float4 v = *(const float4*)(partials + (size_t)g * NB * NPIX + i);
        s.x += v.x; s.y += v.y; s.z += v.z; s.w += v.w;
    }
    *(float4*)(out + i) = s;
}

extern "C" void kernel_launch(void* const* d_in, const int* in_sizes, int n_in,
                              void* d_out, int out_size, void* d_ws, size_t ws_size,
                              hipStream_t stream) {
    const float* sino  = (const float*)d_in[0];
    const float* alpha = (const float*)d_in[1];
    const float* apod  = (const float*)d_in[2];
    const int*   k0    = (const int*)d_in[3];
    const void*  valid = d_in[4];

    float*  out = (float*)d_out;
    double* wsd = (double*)d_ws;
    float*  wsf = (float*)((char*)d_ws + 4096);
    __half* S16 = (__half*)((char*)d_ws + WS_S16_OFF);
    uint4*  pS  = (uint4*)((char*)d_ws + WS_PT_OFF);
    float*  parts = (float*)((char*)d_ws + WS_PT_OFF);

    k_stats   <<<256,  256, 0, stream>>>(sino, wsd);
    k_finalize<<<1,    256, 0, stream>>>(apod, (const unsigned char*)valid, wsd, wsf);
    k_build   <<<1024, 256, 0, stream>>>(sino, wsf, S16);
    if (ws_size >= WS11_REQUIRED) {
        k_das11  <<<2048, 256, 0, stream>>>(k0, alpha, valid, S16, wsf, pS);
        k_reduce3<<<256,  256, 0, stream>>>(pS, out);
    } else {
        k_das2  <<<2048, 1024, 0, stream>>>(k0, alpha, valid, S16, wsf, parts);
        k_reduce<<<512,   256, 0, stream>>>(parts, out);
    }
}

// Round 15
// 76.646 us; speedup vs baseline: 1.3406x; 1.3406x over previous
//
#include <hip/hip_runtime.h>
#include <hip/hip_fp16.h>

#define NB    8
#define NDET  128
#define NT    2048
#define NPIX  65536            // 256*256
#define NELEM (NDET * NT)      // 262144 per batch
#define NGRP  32               // detector groups of 4

// ws layout (bytes):
//   0       : double partials [256][2]  (sum, sumsq per reduction block)
//   4096    : float  wsf[0..7] mean, [8..15] inv_std, uint [16] valid-mode,
//             [17] 1/norm, [32..159] apodn[d]
//   8192    : __half S16[NDET][NT][NB]  (4 MiB)
//   +4M     : __half pT tile-major [tile=p>>6][g][px&63][8]  (32 MiB)
//             (das2 fallback reuses this region as float partials[8][NB][NPIX])

#define WS_S16_OFF   8192
#define WS_PT_OFF    (8192 + (size_t)NDET * NT * NB * 2)
#define WS13_REQUIRED (WS_PT_OFF + (size_t)NGRP * NPIX * NB * 2)

__global__ __launch_bounds__(256) void k_stats(const float* __restrict__ sino,
                                               double* __restrict__ wsd) {
    const int bx = blockIdx.x;            // 0..255
    const int b = bx >> 5, i = bx & 31;   // batch, chunk
    const float4* src = (const float4*)(sino + (size_t)b * NELEM);
    const int base = i * 2048;            // 2048 float4 per chunk
    double s = 0.0, ss = 0.0;
    for (int r = 0; r < 8; ++r) {
        float4 v = src[base + r * 256 + threadIdx.x];
        double d0 = v.x, d1 = v.y, d2 = v.z, d3 = v.w;
        s  += d0 + d1 + d2 + d3;
        ss += d0 * d0 + d1 * d1 + d2 * d2 + d3 * d3;
    }
    for (int off = 32; off; off >>= 1) {
        s  += __shfl_down(s, off);
        ss += __shfl_down(ss, off);
    }
    __shared__ double lds[8];
    const int wave = threadIdx.x >> 6;
    if ((threadIdx.x & 63) == 0) { lds[wave * 2] = s; lds[wave * 2 + 1] = ss; }
    __syncthreads();
    if (threadIdx.x == 0) {
        double S = 0, SS = 0;
        for (int w = 0; w < 4; ++w) { S += lds[w * 2]; SS += lds[w * 2 + 1]; }
        wsd[bx * 2] = S; wsd[bx * 2 + 1] = SS;
    }
}

__global__ __launch_bounds__(256) void k_finalize(const float* __restrict__ apod,
                                                  const unsigned char* __restrict__ validb,
                                                  const double* __restrict__ wsd,
                                                  float* __restrict__ wsf) {
    __shared__ float sap[NDET];
    __shared__ int sflag;
    const int t = threadIdx.x;
    if (t == 0) sflag = 0;
    if (t < NDET) sap[t] = apod[t];
    // Detect `valid` element width. numpy bool -> 1 byte/elem: bytes at
    // offset%4==1 are ~99% ones somewhere in 64KB. int32/f32: always 0.
    int local = 0;
    {
        const unsigned char* vb = validb + t * 256;
        for (int j = 1; j < 256; j += 4) local |= (vb[j] != 0);
    }
    __syncthreads();
    if (local) atomicOr(&sflag, 1);
    if (t < NB) {
        double S = 0, SS = 0;
        for (int i = 0; i < 32; ++i) {
            S  += wsd[(t * 32 + i) * 2];
            SS += wsd[(t * 32 + i) * 2 + 1];
        }
        double mean = S / (double)NELEM;
        double var  = SS / (double)NELEM - mean * mean;
        double istd = 1.0 / sqrt(var + (double)(1.1920928955078125e-07f));
        wsf[t]     = (float)mean;
        wsf[8 + t] = (float)istd;
    }
    if (t == 0) {
        double a = 0;
        for (int d = 0; d < NDET; ++d) a += (double)sap[d];
        float norm = fmaxf((float)a, 1.1754943508222875e-38f);
        wsf[17] = 1.0f / norm;
    }
    __syncthreads();
    if (t < NDET) wsf[32 + t] = sap[t] * wsf[17];
    if (t == 0) ((unsigned int*)wsf)[16] = (unsigned int)(sflag != 0);
}

__global__ __launch_bounds__(256) void k_build(const float* __restrict__ sino,
                                               const float* __restrict__ wsf,
                                               __half* __restrict__ S16) {
    const int dt = blockIdx.x * 256 + threadIdx.x;   // d*NT + t
    union { uint4 q; __half h[8]; } u;
#pragma unroll
    for (int b = 0; b < NB; ++b) {
        float x = sino[(size_t)b * NELEM + dt];
        u.h[b] = __float2half((x - wsf[b]) * wsf[8 + b]);
    }
    *(uint4*)(S16 + (size_t)dt * 8) = u.q;
}

__device__ __forceinline__ float2 h2f(unsigned int w) {
    __half2 h;
    *reinterpret_cast<unsigned int*>(&h) = w;
    return __half22float2(h);
}

__device__ __forceinline__ int   pick4i(int a, int b, int c, int d, int j) {
    int ra = (j & 1) ? b : a, rb = (j & 1) ? d : c; return (j & 2) ? rb : ra;
}
__device__ __forceinline__ float pick4f(float a, float b, float c, float d, int j) {
    float ra = (j & 1) ? b : a, rb = (j & 1) ? d : c; return (j & 2) ? rb : ra;
}

// ---- das13: fused pack+DAS, barrier-free. Block (x=blk&7, sub, chunk) owns
// group g = x*4+sub with its 128KB S16 slice in LDS (das7 structure).
// Per wave, per 64-px iter:
//   LOAD (dense): lane=(q=l&3, pxo=l>>2); 4 sets j: e = px*512B + x*64 + q*16
//     -> 16 fully-used 64B lines per instr, line shared by the XCD's 4
//     sibling blocks via L2 (pack's proven pattern). Double-buffered 1 iter.
//   PERMUTE: final lane m needs quad (sub, px=m): source lane ((m&15)<<2)|sub
//     from set j=m>>4 -> 4x __shfl + select per reg. No LDS, no barriers.
//   GATHER: das7 inner loop from SL; coalesced 1KB pT store per wave.
// Cold LUT stream (~34us floor) overlaps LDS gathers (no MSHR contention).
__global__ __launch_bounds__(1024) void k_das13(const int* __restrict__ k0,
                                                const float* __restrict__ alpha,
                                                const void* __restrict__ valid,
                                                const __half* __restrict__ S16,
                                                const float* __restrict__ wsf,
                                                uint4* __restrict__ pT) {
    __shared__ __align__(16) __half SL[4 * NT * NB];   // 128 KiB
    const int x     = blockIdx.x & 7;
    const int sub   = (blockIdx.x >> 3) & 3;
    const int chunk = blockIdx.x >> 5;                 // 0..7
    const int g     = x * 4 + sub;                     // 0..31
    // stage this group's 128KB S16 slice (contiguous)
    {
        const uint4* src = (const uint4*)(S16 + (size_t)g * 4 * NT * NB);
        uint4* dst = (uint4*)SL;
#pragma unroll
        for (int i = 0; i < 8; ++i)
            dst[i * 1024 + threadIdx.x] = src[i * 1024 + threadIdx.x];
    }
    __syncthreads();                                   // only barrier

    const unsigned int mode = ((const unsigned int*)wsf)[16];
    float apn[4];
#pragma unroll
    for (int j = 0; j < 4; ++j) apn[j] = wsf[32 + g * 4 + j];

    const int tid  = (int)threadIdx.x;
    const int w    = tid >> 6;                         // wave 0..15
    const int lane = tid & 63;
    const int q    = lane & 3;                         // load-role: quad
    const int pxo  = lane >> 2;                        // load-role: pixel 0..15
    const int srcl = ((lane & 15) << 2) | sub;         // permute source lane
    const int jsel = lane >> 4;                        // permute set select
    const int pw   = chunk * 8192 + w * 512;           // wave's first pixel
    const int ebase = x * 16 + q * 4;                  // det element offset

    int4 kn[4]; float4 an[4]; unsigned int vn[4];
#define LOADSETS(IT)                                                          \
    {                                                                         \
        _Pragma("unroll")                                                     \
        for (int j = 0; j < 4; ++j) {                                         \
            const size_t e = (size_t)(pw + (IT) * 64 + j * 16 + pxo) * NDET + ebase; \
            kn[j] = *(const int4*)(k0 + e);                                   \
            an[j] = *(const float4*)(alpha + e);                              \
            if (mode) {                                                       \
                vn[j] = *(const unsigned int*)((const unsigned char*)valid + e); \
            } else {                                                          \
                uint4 v = *(const uint4*)((const unsigned int*)valid + e);    \
                vn[j] = (v.x ? 1u : 0u) | (v.y ? 2u : 0u) |                   \
                        (v.z ? 4u : 0u) | (v.w ? 8u : 0u);                    \
            }                                                                 \
        }                                                                     \
    }

    LOADSETS(0)
    for (int it = 0; it < 8; ++it) {
        int4 kc[4]; float4 ac[4]; unsigned int vc[4];
#pragma unroll
        for (int j = 0; j < 4; ++j) { kc[j] = kn[j]; ac[j] = an[j]; vc[j] = vn[j]; }
        if (it < 7) LOADSETS(it + 1)                   // issue next iter early

        // permute to lane=pixel
        int kk[4]; float aa[4]; unsigned int vb;
#pragma unroll
        for (int cmp = 0; cmp < 4; ++cmp) {
            int t0 = __shfl(((const int*)&kc[0])[cmp], srcl);
            int t1 = __shfl(((const int*)&kc[1])[cmp], srcl);
            int t2 = __shfl(((const int*)&kc[2])[cmp], srcl);
            int t3 = __shfl(((const int*)&kc[3])[cmp], srcl);
            kk[cmp] = pick4i(t0, t1, t2, t3, jsel);
            float f0 = __shfl(((const float*)&ac[0])[cmp], srcl);
            float f1 = __shfl(((const float*)&ac[1])[cmp], srcl);
            float f2 = __shfl(((const float*)&ac[2])[cmp], srcl);
            float f3 = __shfl(((const float*)&ac[3])[cmp], srcl);
            aa[cmp] = pick4f(f0, f1, f2, f3, jsel);
        }
        {
            int t0 = __shfl((int)vc[0], srcl);
            int t1 = __shfl((int)vc[1], srcl);
            int t2 = __shfl((int)vc[2], srcl);
            int t3 = __shfl((int)vc[3], srcl);
            unsigned int vr = (unsigned int)pick4i(t0, t1, t2, t3, jsel);
            vb = mode ? (((vr & 0xffu) ? 1u : 0u) | ((vr & 0xff00u) ? 2u : 0u) |
                         ((vr & 0xff0000u) ? 4u : 0u) | ((vr & 0xff000000u) ? 8u : 0u))
                      : vr;
        }

        // gather from SL (das7 inner)
        float acc[NB] = {0.f, 0.f, 0.f, 0.f, 0.f, 0.f, 0.f, 0.f};
#pragma unroll
        for (int j = 0; j < 4; ++j) {
            const float wgt = ((vb >> j) & 1u) ? apn[j] : 0.0f;
            const float wb  = wgt * aa[j];
            const float wa  = wgt - wb;
            const uint4* s = (const uint4*)(SL + ((size_t)(j * NT + kk[j]) << 3));
            uint4 q0 = s[0];   // tap k,   8 batches
            uint4 q1 = s[1];   // tap k+1, 8 batches
            const unsigned int w0[4] = {q0.x, q0.y, q0.z, q0.w};
            const unsigned int w1[4] = {q1.x, q1.y, q1.z, q1.w};
#pragma unroll
            for (int h = 0; h < 4; ++h) {
                float2 f0 = h2f(w0[h]);
                float2 f1 = h2f(w1[h]);
                acc[2 * h]     += wa * f0.x + wb * f1.x;
                acc[2 * h + 1] += wa * f0.y + wb * f1.y;
            }
        }
        union { uint4 qq; __half2 h[4]; } o;
#pragma unroll
        for (int h = 0; h < 4; ++h)
            o.h[h] = __floats2half2_rn(acc[2 * h], acc[2 * h + 1]);
        const int p = pw + it * 64 + lane;
        pT[(size_t)(p >> 6) * 2048 + g * 64 + (p & 63)] = o.qq;   // 1KB/wave
    }
#undef LOADSETS
}

__global__ __launch_bounds__(256) void k_reduce2(const __half* __restrict__ pT,
                                                 float* __restrict__ out) {
    const int p = blockIdx.x * 256 + threadIdx.x;
    const int tile = p >> 6, pl = p & 63;
    const uint4* pq = (const uint4*)pT;
    float acc[NB] = {0.f, 0.f, 0.f, 0.f, 0.f, 0.f, 0.f, 0.f};
#pragma unroll
    for (int g = 0; g < NGRP; ++g) {
        union { uint4 q; __half2 h[4]; } u;
        u.q = pq[(size_t)tile * 2048 + g * 64 + pl];
#pragma unroll
        for (int h = 0; h < 4; ++h) {
            float2 f = __half22float2(u.h[h]);
            acc[2 * h]     += f.x;
            acc[2 * h + 1] += f.y;
        }
    }
#pragma unroll
    for (int b = 0; b < NB; ++b)
        out[(size_t)b * NPIX + p] = acc[b];
}

// ---- fallback: XCD-sliced L2-gather DAS (round-2 kernel) ----
__global__ __launch_bounds__(1024) void k_das2(const int* __restrict__ k0,
                                               const float* __restrict__ alpha,
                                               const void* __restrict__ valid,
                                               const __half* __restrict__ S16,
                                               const float* __restrict__ wsf,
                                               float* __restrict__ partials) {
    const int px = threadIdx.x & 255;
    const int dc = threadIdx.x >> 8;
    const int slice = blockIdx.x & 7;
    const int chunk = blockIdx.x >> 3;
    const int p  = chunk * 256 + px;
    const int d0 = slice * 16 + dc * 4;
    const unsigned int mode = ((const unsigned int*)wsf)[16];
    const float* apodn = wsf + 32;

    float acc[NB] = {0.f, 0.f, 0.f, 0.f, 0.f, 0.f, 0.f, 0.f};
    const size_t lbase = (size_t)p * NDET + d0;

    int4   k4 = *(const int4*)(k0 + lbase);
    float4 a4 = *(const float4*)(alpha + lbase);
    unsigned int vbits;
    if (mode) {
        unsigned int v4 = *(const unsigned int*)((const unsigned char*)valid + lbase);
        vbits = ((v4 & 0xffu) ? 1u : 0u) | (((v4 >> 8) & 0xffu) ? 2u : 0u) |
                (((v4 >> 16) & 0xffu) ? 4u : 0u) | ((v4 >> 24) ? 8u : 0u);
    } else {
        uint4 v4 = *(const uint4*)((const unsigned int*)valid + lbase);
        vbits = (v4.x ? 1u : 0u) | (v4.y ? 2u : 0u) | (v4.z ? 4u : 0u) | (v4.w ? 8u : 0u);
    }
    const int   kk[4] = {k4.x, k4.y, k4.z, k4.w};
    const float aa[4] = {a4.x, a4.y, a4.z, a4.w};
#pragma unroll
    for (int j = 0; j < 4; ++j) {
        const int d = d0 + j;
        const float w  = ((vbits >> j) & 1u) ? apodn[d] : 0.0f;
        const float wb = w * aa[j];
        const float wa = w - wb;
        const uint4* s = (const uint4*)(S16 + ((size_t)(d * NT + kk[j]) << 3));
        uint4 q0 = s[0];
        uint4 q1 = s[1];
        const unsigned int w0[4] = {q0.x, q0.y, q0.z, q0.w};
        const unsigned int w1[4] = {q1.x, q1.y, q1.z, q1.w};
#pragma unroll
        for (int h = 0; h < 4; ++h) {
            float2 f0 = h2f(w0[h]);
            float2 f1 = h2f(w1[h]);
            acc[2 * h]     += wa * f0.x + wb * f1.x;
            acc[2 * h + 1] += wa * f0.y + wb * f1.y;
        }
    }

    __shared__ float red[1024][9];
#pragma unroll
    for (int b = 0; b < NB; ++b) red[threadIdx.x][b] = acc[b];
    __syncthreads();
    if (dc == 0) {
#pragma unroll
        for (int b = 0; b < NB; ++b) {
            float v = red[px][b] + red[px + 256][b] + red[px + 512][b] + red[px + 768][b];
            partials[((size_t)slice * NB + b) * NPIX + p] = v;
        }
    }
}

__global__ __launch_bounds__(256) void k_reduce(const float* __restrict__ partials,
                                                float* __restrict__ out) {
    const int i = (blockIdx.x * 256 + threadIdx.x) * 4;
    float4 s = {0.f, 0.f, 0.f, 0.f};
#pragma unroll
    for (int g = 0; g < 8; ++g) {
        float4 v = *(const float4*)(partials + (size_t)g * NB * NPIX + i);
        s.x += v.x; s.y += v.y; s.z += v.z; s.w += v.w;
    }
    *(float4*)(out + i) = s;
}

extern "C" void kernel_launch(void* const* d_in, const int* in_sizes, int n_in,
                              void* d_out, int out_size, void* d_ws, size_t ws_size,
                              hipStream_t stream) {
    const float* sino  = (const float*)d_in[0];
    const float* alpha = (const float*)d_in[1];
    const float* apod  = (const float*)d_in[2];
    const int*   k0    = (const int*)d_in[3];
    const void*  valid = d_in[4];

    float*  out = (float*)d_out;
    double* wsd = (double*)d_ws;
    float*  wsf = (float*)((char*)d_ws + 4096);
    __half* S16 = (__half*)((char*)d_ws + WS_S16_OFF);
    uint4*  pT  = (uint4*)((char*)d_ws + WS_PT_OFF);
    float*  parts = (float*)((char*)d_ws + WS_PT_OFF);

    k_stats   <<<256,  256, 0, stream>>>(sino, wsd);
    k_finalize<<<1,    256, 0, stream>>>(apod, (const unsigned char*)valid, wsd, wsf);
    k_build   <<<1024, 256, 0, stream>>>(sino, wsf, S16);
    if (ws_size >= WS13_REQUIRED) {
        k_das13  <<<256, 1024, 0, stream>>>(k0, alpha, valid, S16, wsf, pT);
        k_reduce2<<<256,  256, 0, stream>>>((const __half*)pT, out);
    } else {
        k_das2  <<<2048, 1024, 0, stream>>>(k0, alpha, valid, S16, wsf, parts);
        k_reduce<<<512,   256, 0, stream>>>(parts, out);
    }
}

// Round 17
// 69.878 us; speedup vs baseline: 1.4704x; 1.0969x over previous
//
#include <hip/hip_runtime.h>
#include <hip/hip_fp16.h>

#define NB    8
#define NDET  128
#define NT    2048
#define NPIX  65536            // 256*256
#define NELEM (NDET * NT)      // 262144 per batch
#define NGRP  32               // detector groups of 4

// ws layout (bytes):
//   0       : double partials [256][2]  (sum, sumsq per reduction block)
//   4096    : float  wsf[0..7] mean, [8..15] inv_std, uint [16] valid-mode,
//             [17] 1/norm, [32..159] apodn[d]
//   8192    : __half S16[NDET][NT][NB]  (4 MiB)
//   +4M     : 32 MiB region shared in-place, TILE-MAJOR layout:
//               uint4 pk[tile=p>>6][g][px&63]   (tile stride 32KB)
//               k_pack6 writes it; k_das7 reads+overwrites in place with fp16
//               partials; k_reduce2 reads those.
//             (das2 fallback reuses this region as float partials[8][NB][NPIX])

#define WS_S16_OFF   8192
#define WS_PT_OFF    (8192 + (size_t)NDET * NT * NB * 2)
#define WS7_REQUIRED (WS_PT_OFF + (size_t)NGRP * NPIX * NB * 2)

__global__ __launch_bounds__(256) void k_stats(const float* __restrict__ sino,
                                               double* __restrict__ wsd) {
    const int bx = blockIdx.x;            // 0..255
    const int b = bx >> 5, i = bx & 31;   // batch, chunk
    const float4* src = (const float4*)(sino + (size_t)b * NELEM);
    const int base = i * 2048;            // 2048 float4 per chunk
    double s = 0.0, ss = 0.0;
    for (int r = 0; r < 8; ++r) {
        float4 v = src[base + r * 256 + threadIdx.x];
        double d0 = v.x, d1 = v.y, d2 = v.z, d3 = v.w;
        s  += d0 + d1 + d2 + d3;
        ss += d0 * d0 + d1 * d1 + d2 * d2 + d3 * d3;
    }
    for (int off = 32; off; off >>= 1) {
        s  += __shfl_down(s, off);
        ss += __shfl_down(ss, off);
    }
    __shared__ double lds[8];
    const int wave = threadIdx.x >> 6;
    if ((threadIdx.x & 63) == 0) { lds[wave * 2] = s; lds[wave * 2 + 1] = ss; }
    __syncthreads();
    if (threadIdx.x == 0) {
        double S = 0, SS = 0;
        for (int w = 0; w < 4; ++w) { S += lds[w * 2]; SS += lds[w * 2 + 1]; }
        wsd[bx * 2] = S; wsd[bx * 2 + 1] = SS;
    }
}

__global__ __launch_bounds__(256) void k_finalize(const float* __restrict__ apod,
                                                  const unsigned char* __restrict__ validb,
                                                  const double* __restrict__ wsd,
                                                  float* __restrict__ wsf) {
    __shared__ float sap[NDET];
    __shared__ int sflag;
    const int t = threadIdx.x;
    if (t == 0) sflag = 0;
    if (t < NDET) sap[t] = apod[t];
    // Detect `valid` element width. numpy bool -> 1 byte/elem: bytes at
    // offset%4==1 are ~99% ones somewhere in 64KB. int32/f32: always 0.
    int local = 0;
    {
        const unsigned char* vb = validb + t * 256;
        for (int j = 1; j < 256; j += 4) local |= (vb[j] != 0);
    }
    __syncthreads();
    if (local) atomicOr(&sflag, 1);
    if (t < NB) {
        double S = 0, SS = 0;
        for (int i = 0; i < 32; ++i) {
            S  += wsd[(t * 32 + i) * 2];
            SS += wsd[(t * 32 + i) * 2 + 1];
        }
        double mean = S / (double)NELEM;
        double var  = SS / (double)NELEM - mean * mean;
        double istd = 1.0 / sqrt(var + (double)(1.1920928955078125e-07f));
        wsf[t]     = (float)mean;
        wsf[8 + t] = (float)istd;
    }
    if (t == 0) {
        double a = 0;
        for (int d = 0; d < NDET; ++d) a += (double)sap[d];
        float norm = fmaxf((float)a, 1.1754943508222875e-38f);
        wsf[17] = 1.0f / norm;
    }
    __syncthreads();
    if (t < NDET) wsf[32 + t] = sap[t] * wsf[17];
    if (t == 0) ((unsigned int*)wsf)[16] = (unsigned int)(sflag != 0);
}

__global__ __launch_bounds__(256) void k_build(const float* __restrict__ sino,
                                               const float* __restrict__ wsf,
                                               __half* __restrict__ S16) {
    const int dt = blockIdx.x * 256 + threadIdx.x;   // d*NT + t
    union { uint4 q; __half h[8]; } u;
#pragma unroll
    for (int b = 0; b < NB; ++b) {
        float x = sino[(size_t)b * NELEM + dt];
        u.h[b] = __float2half((x - wsf[b]) * wsf[8 + b]);
    }
    *(uint4*)(S16 + (size_t)dt * 8) = u.q;
}

__device__ __forceinline__ float2 h2f(unsigned int w) {
    __half2 h;
    *reinterpret_cast<unsigned int*>(&h) = w;
    return __half22float2(h);
}

// ---- pack v6b: async global_load_lds staging (zero dest VGPRs -> maximal
// in-flight lines: 18 async 1KB wave-chunks outstanding per wave, 8 waves/CU).
// Block = 64-px tile: k0 32KB + alpha 32KB + valid 8KB staged to LDS LINEARLY
// (dense global src = linear LDS dest, rule-21 compliant), ONE vmcnt(0)
// + barrier, then pack unit-major (lane = unit -> conflict-free LDS reads)
// and store TRANSPOSED to tile-major pk: dst[q*64+px] (32-way 16B scatter;
// posted stores into a 32KB-hot L2 tile -- v2 proved this pattern harmless).
// BUGFIX vs R15: store index was dst[px*32+q] (unit-major), reader expects
// [g][px] -> transposed output. Now dst[q*64+px].
// word = (k0 & 0x7FF) | (valid<<11) | (fp16(alpha)<<16)
__global__ __launch_bounds__(256) void k_pack6(const int* __restrict__ k0,
                                               const float* __restrict__ alpha,
                                               const void* __restrict__ valid,
                                               const float* __restrict__ wsf,
                                               uint4* __restrict__ packT) {
    __shared__ __align__(16) int           SK[8192];   // 32 KB
    __shared__ __align__(16) float         SA[8192];   // 32 KB
    __shared__ __align__(16) unsigned char SV[8192];   //  8 KB
    const unsigned int mode = ((const unsigned int*)wsf)[16];
    const int tile = blockIdx.x;           // 0..1023
    const int t = threadIdx.x;
    const int w = t >> 6, lane = t & 63;
    const size_t eb = (size_t)tile * 8192; // element base

    // k0: 32 chunks of 1KB; chunk c = w*8+i (wave-uniform LDS base)
#pragma unroll
    for (int i = 0; i < 8; ++i) {
        const int c = w * 8 + i;
        __builtin_amdgcn_global_load_lds(
            (const __attribute__((address_space(1))) void*)(k0 + eb + c * 256 + lane * 4),
            (__attribute__((address_space(3))) void*)(SK + c * 256), 16, 0, 0);
    }
    // alpha: 32 chunks
#pragma unroll
    for (int i = 0; i < 8; ++i) {
        const int c = w * 8 + i;
        __builtin_amdgcn_global_load_lds(
            (const __attribute__((address_space(1))) void*)(alpha + eb + c * 256 + lane * 4),
            (__attribute__((address_space(3))) void*)(SA + c * 256), 16, 0, 0);
    }
    if (mode) {
        // byte-mode valid: 8 chunks of 1KB
#pragma unroll
        for (int i = 0; i < 2; ++i) {
            const int c = w * 2 + i;
            __builtin_amdgcn_global_load_lds(
                (const __attribute__((address_space(1))) void*)((const unsigned char*)valid + eb + c * 1024 + lane * 16),
                (__attribute__((address_space(3))) void*)(SV + c * 1024), 16, 0, 0);
        }
        asm volatile("s_waitcnt vmcnt(0)" ::: "memory");
        __syncthreads();
    } else {
        // word-mode: 32 words/thread -> fold to bytes -> ds_write (cold path)
        const unsigned int* vw = (const unsigned int*)valid;
        union { uint4 q[2]; unsigned char b[32]; } vb;
#pragma unroll
        for (int i = 0; i < 8; ++i) {
            uint4 v = *(const uint4*)(vw + eb + (size_t)t * 32 + i * 4);
            vb.b[i * 4 + 0] = v.x ? 1 : 0;
            vb.b[i * 4 + 1] = v.y ? 1 : 0;
            vb.b[i * 4 + 2] = v.z ? 1 : 0;
            vb.b[i * 4 + 3] = v.w ? 1 : 0;
        }
        *(uint4*)(SV + t * 32)      = vb.q[0];
        *(uint4*)(SV + t * 32 + 16) = vb.q[1];
        asm volatile("s_waitcnt vmcnt(0)" ::: "memory");
        __syncthreads();
    }

    // pack phase: unit f = i*256+t (px = f>>5, q = f&31), conflict-free LDS
    // reads (lanes consecutive units); store transposed: dst[q*64 + px].
    const uint4* k4 = (const uint4*)SK;
    const uint4* a4 = (const uint4*)SA;
    uint4* dst = packT + (size_t)tile * 2048;
#pragma unroll
    for (int i = 0; i < 8; ++i) {
        const int f  = i * 256 + t;
        const int px = f >> 5, q = f & 31;
        const uint4 kq = k4[f];
        const uint4 aq = a4[f];
        const unsigned int vB = *(const unsigned int*)(SV + f * 4);
        const unsigned int vm = ((vB & 0xffu) ? 1u : 0u) | ((vB & 0xff00u) ? 2u : 0u) |
                                ((vB & 0xff0000u) ? 4u : 0u) | ((vB & 0xff000000u) ? 8u : 0u);
        const int ks[4] = {(int)kq.x, (int)kq.y, (int)kq.z, (int)kq.w};
        float as[4];
        as[0] = __uint_as_float(aq.x); as[1] = __uint_as_float(aq.y);
        as[2] = __uint_as_float(aq.z); as[3] = __uint_as_float(aq.w);
        uint4 o;
        unsigned int* ow = (unsigned int*)&o;
#pragma unroll
        for (int j = 0; j < 4; ++j) {
            __half ha = __float2half_rn(as[j]);
            unsigned short hb = *(unsigned short*)&ha;
            ow[j] = ((unsigned int)ks[j] & 0x7FFu) | (((vm >> j) & 1u) << 11) |
                    ((unsigned int)hb << 16);
        }
        dst[q * 64 + px] = o;              // tile-major [g][px]
    }
}

// ---- LDS-staged DAS v7 (tile-indexed, unchanged): lane = pixel, coalesced
// pk load with rolling prefetch, in-place fp16 partial overwrite.
// XCD-aligned: x = blockIdx&7, g = x*4+sub.
__global__ __launch_bounds__(1024) void k_das7(uint4* pk,            // aliased read/write
                                               const __half* __restrict__ S16,
                                               const float* __restrict__ wsf) {
    __shared__ __align__(16) __half SL[4 * NT * NB];   // 128 KiB
    const int x     = blockIdx.x & 7;
    const int sub   = (blockIdx.x >> 3) & 3;
    const int chunk = blockIdx.x >> 5;                 // 0..7
    const int g     = x * 4 + sub;                     // 0..31
    {
        const uint4* src = (const uint4*)(S16 + (size_t)g * 4 * NT * NB);
        uint4* dst = (uint4*)SL;
#pragma unroll
        for (int i = 0; i < 8; ++i)
            dst[i * 1024 + threadIdx.x] = src[i * 1024 + threadIdx.x];
    }
    __syncthreads();

    float apn[4];
#pragma unroll
    for (int j = 0; j < 4; ++j) apn[j] = wsf[32 + g * 4 + j];

    const int tid = (int)threadIdx.x;
    const size_t idx = ((size_t)(chunk * 128 + (tid >> 6))) * 2048 + g * 64 + (tid & 63);

    uint4 pkb = pk[idx];                               // iter-0 prefetch
    for (int it = 0; it < 8; ++it) {
        const uint4 pkc = pkb;
        if (it < 7) pkb = pk[idx + (size_t)(it + 1) * 32768];

        const unsigned int pw[4] = {pkc.x, pkc.y, pkc.z, pkc.w};
        float acc[NB] = {0.f, 0.f, 0.f, 0.f, 0.f, 0.f, 0.f, 0.f};
#pragma unroll
        for (int j = 0; j < 4; ++j) {
            const unsigned int wj = pw[j];
            const int kk = (int)(wj & 0x7FFu);
            unsigned short hb = (unsigned short)(wj >> 16);
            const float aa = __half2float(*(const __half*)&hb);
            const float w  = (wj & 0x800u) ? apn[j] : 0.0f;
            const float wb = w * aa;
            const float wa = w - wb;
            const uint4* s = (const uint4*)(SL + ((size_t)(j * NT + kk) << 3));
            uint4 q0 = s[0];   // tap k,   8 batches
            uint4 q1 = s[1];   // tap k+1, 8 batches
            const unsigned int w0[4] = {q0.x, q0.y, q0.z, q0.w};
            const unsigned int w1[4] = {q1.x, q1.y, q1.z, q1.w};
#pragma unroll
            for (int h = 0; h < 4; ++h) {
                float2 f0 = h2f(w0[h]);
                float2 f1 = h2f(w1[h]);
                acc[2 * h]     += wa * f0.x + wb * f1.x;
                acc[2 * h + 1] += wa * f0.y + wb * f1.y;
            }
        }
        union { uint4 q; __half2 h[4]; } o;
#pragma unroll
        for (int h = 0; h < 4; ++h)
            o.h[h] = __floats2half2_rn(acc[2 * h], acc[2 * h + 1]);
        pk[idx + (size_t)it * 32768] = o.q;            // overwrite own slot
    }
}

__global__ __launch_bounds__(256) void k_reduce2(const __half* __restrict__ pT,
                                                 float* __restrict__ out) {
    const int p = blockIdx.x * 256 + threadIdx.x;
    const int tile = p >> 6, pl = p & 63;
    const uint4* pq = (const uint4*)pT;
    float acc[NB] = {0.f, 0.f, 0.f, 0.f, 0.f, 0.f, 0.f, 0.f};
#pragma unroll
    for (int g = 0; g < NGRP; ++g) {
        union { uint4 q; __half2 h[4]; } u;
        u.q = pq[(size_t)tile * 2048 + g * 64 + pl];
#pragma unroll
        for (int h = 0; h < 4; ++h) {
            float2 f = __half22float2(u.h[h]);
            acc[2 * h]     += f.x;
            acc[2 * h + 1] += f.y;
        }
    }
#pragma unroll
    for (int b = 0; b < NB; ++b)
        out[(size_t)b * NPIX + p] = acc[b];
}

// ---- fallback: XCD-sliced L2-gather DAS (round-2 kernel) ----
__global__ __launch_bounds__(1024) void k_das2(const int* __restrict__ k0,
                                               const float* __restrict__ alpha,
                                               const void* __restrict__ valid,
                                               const __half* __restrict__ S16,
                                               const float* __restrict__ wsf,
                                               float* __restrict__ partials) {
    const int px = threadIdx.x & 255;
    const int dc = threadIdx.x >> 8;
    const int slice = blockIdx.x & 7;
    const int chunk = blockIdx.x >> 3;
    const int p  = chunk * 256 + px;
    const int d0 = slice * 16 + dc * 4;
    const unsigned int mode = ((const unsigned int*)wsf)[16];
    const float* apodn = wsf + 32;

    float acc[NB] = {0.f, 0.f, 0.f, 0.f, 0.f, 0.f, 0.f, 0.f};
    const size_t lbase = (size_t)p * NDET + d0;

    int4   k4 = *(const int4*)(k0 + lbase);
    float4 a4 = *(const float4*)(alpha + lbase);
    unsigned int vbits;
    if (mode) {
        unsigned int v4 = *(const unsigned int*)((const unsigned char*)valid + lbase);
        vbits = ((v4 & 0xffu) ? 1u : 0u) | (((v4 >> 8) & 0xffu) ? 2u : 0u) |
                (((v4 >> 16) & 0xffu) ? 4u : 0u) | ((v4 >> 24) ? 8u : 0u);
    } else {
        uint4 v4 = *(const uint4*)((const unsigned int*)valid + lbase);
        vbits = (v4.x ? 1u : 0u) | (v4.y ? 2u : 0u) | (v4.z ? 4u : 0u) | (v4.w ? 8u : 0u);
    }
    const int   kk[4] = {k4.x, k4.y, k4.z, k4.w};
    const float aa[4] = {a4.x, a4.y, a4.z, a4.w};
#pragma unroll
    for (int j = 0; j < 4; ++j) {
        const int d = d0 + j;
        const float w  = ((vbits >> j) & 1u) ? apodn[d] : 0.0f;
        const float wb = w * aa[j];
        const float wa = w - wb;
        const uint4* s = (const uint4*)(S16 + ((size_t)(d * NT + kk[j]) << 3));
        uint4 q0 = s[0];
        uint4 q1 = s[1];
        const unsigned int w0[4] = {q0.x, q0.y, q0.z, q0.w};
        const unsigned int w1[4] = {q1.x, q1.y, q1.z, q1.w};
#pragma unroll
        for (int h = 0; h < 4; ++h) {
            float2 f0 = h2f(w0[h]);
            float2 f1 = h2f(w1[h]);
            acc[2 * h]     += wa * f0.x + wb * f1.x;
            acc[2 * h + 1] += wa * f0.y + wb * f1.y;
        }
    }

    __shared__ float red[1024][9];
#pragma unroll
    for (int b = 0; b < NB; ++b) red[threadIdx.x][b] = acc[b];
    __syncthreads();
    if (dc == 0) {
#pragma unroll
        for (int b = 0; b < NB; ++b) {
            float v = red[px][b] + red[px + 256][b] + red[px + 512][b] + red[px + 768][b];
            partials[((size_t)slice * NB + b) * NPIX + p] = v;
        }
    }
}

__global__ __launch_bounds__(256) void k_reduce(const float* __restrict__ partials,
                                                float* __restrict__ out) {
    const int i = (blockIdx.x * 256 + threadIdx.x) * 4;
    float4 s = {0.f, 0.f, 0.f, 0.f};
#pragma unroll
    for (int g = 0; g < 8; ++g) {
        float4 v = *(const float4*)(partials + (size_t)g * NB * NPIX + i);
        s.x += v.x; s.y += v.y; s.z += v.z; s.w += v.w;
    }
    *(float4*)(out + i) = s;
}

extern "C" void kernel_launch(void* const* d_in, const int* in_sizes, int n_in,
                              void* d_out, int out_size, void* d_ws, size_t ws_size,
                              hipStream_t stream) {
    const float* sino  = (const float*)d_in[0];
    const float* alpha = (const float*)d_in[1];
    const float* apod  = (const float*)d_in[2];
    const int*   k0    = (const int*)d_in[3];
    const void*  valid = d_in[4];

    float*  out = (float*)d_out;
    double* wsd = (double*)d_ws;
    float*  wsf = (float*)((char*)d_ws + 4096);
    __half* S16 = (__half*)((char*)d_ws + WS_S16_OFF);
    uint4*  pk  = (uint4*)((char*)d_ws + WS_PT_OFF);
    float*  parts = (float*)((char*)d_ws + WS_PT_OFF);

    k_stats   <<<256,  256, 0, stream>>>(sino, wsd);
    k_finalize<<<1,    256, 0, stream>>>(apod, (const unsigned char*)valid, wsd, wsf);
    k_build   <<<1024, 256, 0, stream>>>(sino, wsf, S16);
    if (ws_size >= WS7_REQUIRED) {
        k_pack6  <<<1024, 256, 0, stream>>>(k0, alpha, valid, wsf, pk);
        k_das7   <<<256, 1024, 0, stream>>>(pk, S16, wsf);
        k_reduce2<<<256,  256, 0, stream>>>((const __half*)pk, out);
    } else {
        k_das2  <<<2048, 1024, 0, stream>>>(k0, alpha, valid, S16, wsf, parts);
        k_reduce<<<512,   256, 0, stream>>>(parts, out);
    }
}